// Round 1
// baseline (3481.312 us; speedup 1.0000x reference)
//
#include <hip/hip_runtime.h>
#include <hip/hip_bf16.h>
#include <cstddef>
#include <cstdint>

// Problem constants
#define NB 32          // batch
#define NS 512         // seq len
#define ND 512         // d_model == hid
#define NG 2048        // 4*hid gate cols per layer

// ws layout (bytes)
#define H0_OFF   0          // [2 parity][32768] bf16 frag-order h, layer0
#define H1_OFF   65536      // same, layer1
#define FLAGS_OFF 131072    // int[128]: [layer][slice]
#define CTRL_BYTES 135168   // memset region (flags + h bufs + slack)
#define XWS_OFF  135168     // bf16 frag-order x: 512*32*512*2 bytes
#define XWS_BYTES (512u*32u*512u*2u)

typedef __attribute__((ext_vector_type(8))) short short8;
typedef __attribute__((ext_vector_type(8))) __bf16 bf16x8;
typedef __attribute__((ext_vector_type(4))) float f32x4;

static __device__ __forceinline__ unsigned short f2bf(float f) {
  __hip_bfloat16 h = __float2bfloat16(f);
  return __builtin_bit_cast(unsigned short, h);
}

static __device__ __forceinline__ short8 pack8(float4 a, float4 b) {
  short8 r;
  r[0] = (short)f2bf(a.x); r[1] = (short)f2bf(a.y);
  r[2] = (short)f2bf(a.z); r[3] = (short)f2bf(a.w);
  r[4] = (short)f2bf(b.x); r[5] = (short)f2bf(b.y);
  r[6] = (short)f2bf(b.z); r[7] = (short)f2bf(b.w);
  return r;
}

// ---------------- Kernel 1: fp32 embedding gather (output 1) ----------------
__global__ __launch_bounds__(256) void gather_f32(const int* __restrict__ src,
                                                  const float* __restrict__ emb,
                                                  float* __restrict__ out1) {
  int tid = blockIdx.x * 256 + threadIdx.x;   // 0 .. 2097151 (float4 granules)
  int bt = tid >> 7;                          // b*512 + t
  int k4 = (tid & 127) << 2;
  int s  = src[bt];
  float4 v = *reinterpret_cast<const float4*>(emb + (size_t)s * ND + k4);
  *reinterpret_cast<float4*>(out1 + (size_t)bt * ND + k4) = v;
}

// ------------- Kernel 2: bf16 x in MFMA A-fragment order (into ws) ----------
// element (t,b,k) -> byte ((t*16 + (k>>5))*2 + (b>>4))*1024 + ((k>>3)&3)*256 + (b&15)*16 + (k&7)*2
__global__ __launch_bounds__(256) void gather_xfrag(const int* __restrict__ src,
                                                    const float* __restrict__ emb,
                                                    unsigned char* __restrict__ xws) {
  int tid = blockIdx.x * 256 + threadIdx.x;   // 0 .. 262143
  int br = tid & 15;
  int mh = (tid >> 4) & 1;
  int kt = (tid >> 5) & 15;
  int t  = tid >> 9;
  int b  = mh * 16 + br;
  int s  = src[b * NS + t];
  const float* row = emb + (size_t)s * ND + kt * 32;
  unsigned char* base = xws + ((size_t)((t * 16 + kt) * 2 + mh)) * 1024 + br * 16;
#pragma unroll
  for (int qq = 0; qq < 4; ++qq) {
    float4 v0 = *reinterpret_cast<const float4*>(row + qq * 8);
    float4 v1 = *reinterpret_cast<const float4*>(row + qq * 8 + 4);
    *reinterpret_cast<short8*>(base + qq * 256) = pack8(v0, v1);
  }
}

// ---------------- Kernel 3: persistent 2-layer LSTM ----------------
// grid = 128 blocks: L = bid>>6, slice = bid&63 (8 hidden units / 32 gate cols each)
// per block: GEMM [32 x 1024] @ [1024 x 32] bf16 -> gates -> h,c update -> publish
template<bool XWS>
__global__ __launch_bounds__(256, 1) void lstm_persist(
    const float* __restrict__ Wk, const float* __restrict__ Wr,
    const float* __restrict__ bias_g,
    const float* __restrict__ x_f32,          // gathered fp32 emb (fallback path)
    const unsigned char* __restrict__ xws,    // frag-order bf16 x
    unsigned char* ws, float* __restrict__ out0) {

  __shared__ __attribute__((aligned(16))) char smem[66048];

  const int tid   = threadIdx.x;
  const int bid   = blockIdx.x;
  const int L     = bid >> 6;
  const int slice = bid & 63;
  const int u0    = slice * 8;
  const int lane  = tid & 63;
  const int wv    = tid >> 6;
  const int m     = wv & 1;    // batch mtile (16 rows)
  const int kh    = wv >> 1;   // K half (16 ktiles of 32)

  const float* WkL = Wk + (size_t)L * 512 * NG;
  const float* WrL = Wr + (size_t)L * 512 * NG;

  // ---- phase 1: stage transposed weight slice into LDS: WT[32 cols][1032 k] bf16
  short* WT = reinterpret_cast<short*>(smem);
  for (int idx = tid; idx < 1024 * 32; idx += 256) {
    int k = idx >> 5, c = idx & 31;
    int gc = (c >> 3) * 512 + u0 + (c & 7);        // cols ordered [i8|f8|g8|o8]
    float v = (k < 512) ? WkL[(size_t)k * NG + gc]
                        : WrL[(size_t)(k - 512) * NG + gc];
    WT[c * 1032 + k] = (short)f2bf(v);
  }
  __syncthreads();

  // ---- preload static B fragments into VGPRs (32 frags = 128 VGPRs/wave)
  short8 Bf[2][16];
  {
    int colr = lane & 15;
    int q    = lane >> 4;
#pragma unroll
    for (int n = 0; n < 2; ++n)
#pragma unroll
      for (int kt2 = 0; kt2 < 16; ++kt2) {
        int k = (kh * 16 + kt2) * 32 + q * 8;
        Bf[n][kt2] = *reinterpret_cast<const short8*>(WT + (n * 16 + colr) * 1032 + k);
      }
  }
  __syncthreads();

  // ---- LDS reused: z partials [2 kh][32 b][33] f32 + bias[32]
  float* zbuf = reinterpret_cast<float*>(smem);   // 2112 floats
  float* blds = zbuf + 2112;                      // 32 floats
  if (tid < 32) {
    int gc = (tid >> 3) * 512 + u0 + (tid & 7);
    blds[tid] = bias_g[L * NG + gc];
  }
  __syncthreads();

  int* flags = reinterpret_cast<int*>(ws + FLAGS_OFF);
  unsigned char* h0buf = ws + H0_OFF;
  unsigned char* h1buf = ws + H1_OFF;

  // epilogue thread mapping: (b,u) and publish offset into frag-order h buffer
  const int eb = tid >> 3, eu = tid & 7;
  const int pub_off = ((u0 >> 5) * 2 + (eb >> 4)) * 1024 +
                      ((u0 & 31) >> 3) * 256 + (eb & 15) * 16 + eu * 2;

  float creg = 0.f;
  bool gaveup = false;

  for (int t = 0; t < NS; ++t) {
    short8 af[16];

    // x prefetch (layer 0, kh==0 waves): independent of flags
    if (L == 0 && kh == 0) {
      if (XWS) {
        const unsigned char* xb = xws + ((size_t)(t * 16) * 2 + m) * 1024 + lane * 16;
#pragma unroll
        for (int kt2 = 0; kt2 < 16; ++kt2)
          af[kt2] = *reinterpret_cast<const short8*>(xb + (size_t)kt2 * 2048);
      } else {
        int bb = m * 16 + (lane & 15);
        const float* xr = x_f32 + ((size_t)bb * NS + t) * ND + (lane >> 4) * 8;
#pragma unroll
        for (int kt2 = 0; kt2 < 16; ++kt2) {
          float4 v0 = *reinterpret_cast<const float4*>(xr + kt2 * 32);
          float4 v1 = *reinterpret_cast<const float4*>(xr + kt2 * 32 + 4);
          af[kt2] = pack8(v0, v1);
        }
      }
    }

    // poll: wave 0 only. layer0 needs flag0>=t (h0[t-1]) and flag1>=t-1 (anti-overwrite);
    // layer1 needs flag0>=t+1 (h0[t]) and flag1>=t (h1[t-1]).
    if (wv == 0 && !gaveup) {
      int n0 = (L == 0) ? t : t + 1;
      int n1 = (L == 0) ? t - 1 : t;
      int spin = 0;
      for (;; ++spin) {
        int f0 = __hip_atomic_load(flags + lane,      __ATOMIC_RELAXED, __HIP_MEMORY_SCOPE_AGENT);
        int f1 = __hip_atomic_load(flags + 64 + lane, __ATOMIC_RELAXED, __HIP_MEMORY_SCOPE_AGENT);
        if (__all(f0 >= n0 && f1 >= n1)) break;
        if (spin > (1 << 20)) { gaveup = true; break; }   // fail-safe: no hang
        __builtin_amdgcn_s_sleep(1);
      }
    }
    __syncthreads();

    // h fragment loads (agent-scope atomics -> coherence point)
    if (!(L == 0 && kh == 0)) {
      const unsigned char* hb;
      if (L == 0)      hb = h0buf + ((t - 1) & 1) * 32768;          // h0[t-1]
      else if (kh == 0) hb = h0buf + (t & 1) * 32768;               // h0[t]
      else              hb = h1buf + ((t - 1) & 1) * 32768;         // h1[t-1]
      const unsigned char* ha = hb + (size_t)m * 1024 + lane * 16;
#pragma unroll
      for (int kt2 = 0; kt2 < 16; ++kt2) {
        unsigned long long* ap = reinterpret_cast<unsigned long long*>(&af[kt2]);
        unsigned long long* p  = reinterpret_cast<unsigned long long*>(
            const_cast<unsigned char*>(ha) + (size_t)kt2 * 2048);
        ap[0] = __hip_atomic_load(p,     __ATOMIC_RELAXED, __HIP_MEMORY_SCOPE_AGENT);
        ap[1] = __hip_atomic_load(p + 1, __ATOMIC_RELAXED, __HIP_MEMORY_SCOPE_AGENT);
      }
    }

    // MFMA: 16 ktiles x 2 ntiles, fp32 accum
    f32x4 acc0 = {0.f, 0.f, 0.f, 0.f}, acc1 = {0.f, 0.f, 0.f, 0.f};
#pragma unroll
    for (int kt2 = 0; kt2 < 16; ++kt2) {
      bf16x8 a = __builtin_bit_cast(bf16x8, af[kt2]);
      acc0 = __builtin_amdgcn_mfma_f32_16x16x32_bf16(a, __builtin_bit_cast(bf16x8, Bf[0][kt2]), acc0, 0, 0, 0);
      acc1 = __builtin_amdgcn_mfma_f32_16x16x32_bf16(a, __builtin_bit_cast(bf16x8, Bf[1][kt2]), acc1, 0, 0, 0);
    }

    // z partials -> LDS (C layout: col = lane&15, row = (lane>>4)*4 + reg)
    {
      int r0 = m * 16 + (lane >> 4) * 4;
      int cc = lane & 15;
      float* zp = zbuf + kh * (32 * 33);
#pragma unroll
      for (int r = 0; r < 4; ++r) {
        zp[(r0 + r) * 33 + cc]      = acc0[r];
        zp[(r0 + r) * 33 + 16 + cc] = acc1[r];
      }
    }
    __syncthreads();

    // epilogue: thread (eb, eu) owns one hidden unit
    {
      float zi = zbuf[eb * 33 + eu]      + zbuf[1056 + eb * 33 + eu]      + blds[eu];
      float zf = zbuf[eb * 33 + 8 + eu]  + zbuf[1056 + eb * 33 + 8 + eu]  + blds[8 + eu];
      float zg = zbuf[eb * 33 + 16 + eu] + zbuf[1056 + eb * 33 + 16 + eu] + blds[16 + eu];
      float zo = zbuf[eb * 33 + 24 + eu] + zbuf[1056 + eb * 33 + 24 + eu] + blds[24 + eu];
      float ig = 1.f / (1.f + __expf(-zi));
      float fg = 1.f / (1.f + __expf(-zf));
      float e2 = __expf(-2.f * zg);
      float gg = (1.f - e2) / (1.f + e2);
      float og = 1.f / (1.f + __expf(-zo));
      creg = fg * creg + ig * gg;
      float ec = __expf(-2.f * creg);
      float th = (1.f - ec) / (1.f + ec);
      float hv = og * th;

      if (L == 1) out0[((size_t)eb * NS + t) * ND + u0 + eu] = hv;   // final output

      unsigned int hu = f2bf(hv);
      unsigned int hi = (unsigned int)__shfl_down((int)hu, 1);
      if ((eu & 1) == 0) {
        unsigned int packed = (hu & 0xffffu) | (hi << 16);
        unsigned char* dst = ((L == 0) ? h0buf : h1buf) + (t & 1) * 32768 + pub_off;
        __hip_atomic_store(reinterpret_cast<unsigned int*>(dst), packed,
                           __ATOMIC_RELAXED, __HIP_MEMORY_SCOPE_AGENT);
      }
    }
    __syncthreads();   // drains all waves' publish stores (vmcnt(0) before barrier)

    if (tid == 0)
      __hip_atomic_store(flags + L * 64 + slice, t + 1,
                         __ATOMIC_RELEASE, __HIP_MEMORY_SCOPE_AGENT);
  }
}

extern "C" void kernel_launch(void* const* d_in, const int* in_sizes, int n_in,
                              void* d_out, int out_size, void* d_ws, size_t ws_size,
                              hipStream_t stream) {
  const int*   src = (const int*)d_in[0];
  // d_in[1] = source_len (unused by the reference computation)
  const float* emb = (const float*)d_in[2];
  const float* Wk  = (const float*)d_in[3];
  const float* Wr  = (const float*)d_in[4];
  const float* bg  = (const float*)d_in[5];

  float* out0 = (float*)d_out;                        // LSTM output [32,512,512]
  float* out1 = out0 + (size_t)NB * NS * ND;          // source_emb [32,512,512]
  unsigned char* ws = (unsigned char*)d_ws;

  // output 1: embedding gather (also the fp32 x source for the fallback path)
  gather_f32<<<8192, 256, 0, stream>>>(src, emb, out1);

  // zero flags + h double buffers every call (ws is re-poisoned by the harness)
  hipMemsetAsync(d_ws, 0, CTRL_BYTES, stream);

  bool xws_ok = ws_size >= (size_t)XWS_OFF + (size_t)XWS_BYTES;
  if (xws_ok) {
    gather_xfrag<<<1024, 256, 0, stream>>>(src, emb, ws + XWS_OFF);
    lstm_persist<true><<<128, 256, 0, stream>>>(Wk, Wr, bg, out1, ws + XWS_OFF, ws, out0);
  } else {
    lstm_persist<false><<<128, 256, 0, stream>>>(Wk, Wr, bg, out1, ws + XWS_OFF, ws, out0);
  }
}